// Round 5
// baseline (535.809 us; speedup 1.0000x reference)
//
#include <hip/hip_runtime.h>
#include <hip/hip_bf16.h>

typedef unsigned short u16;
typedef __bf16 bf16x8 __attribute__((ext_vector_type(8)));
typedef float f32x4 __attribute__((ext_vector_type(4)));

#define B_IMG 128
#define NOBJ  36
#define NNODE (B_IMG * NOBJ)

__device__ __forceinline__ float b2f(u16 u) {
    union { unsigned int i; float f; } v; v.i = ((unsigned int)u) << 16; return v.f;
}
__device__ __forceinline__ u16 f2b(float f) {
    union { float f; unsigned int i; } v; v.f = f;
    unsigned int u = v.i;
    return (u16)((u + 0x7fffu + ((u >> 16) & 1u)) >> 16);   // RNE
}

// ---------------------------------------------------------------------------
// fp32 -> bf16 packer. n4 = elems/4.
// ---------------------------------------------------------------------------
__global__ __launch_bounds__(256)
void conv_mat(const float* __restrict__ src, u16* __restrict__ dst, int n4) {
    const int i = blockIdx.x * 256 + threadIdx.x;
    if (i >= n4) return;
    const float4 f = ((const float4*)src)[i];
    ushort4 o; o.x = f2b(f.x); o.y = f2b(f.y); o.z = f2b(f.z); o.w = f2b(f.w);
    ((ushort4*)dst)[i] = o;
}

// ---------------------------------------------------------------------------
// fused fp32->bf16 convert + transpose: dst[c*R + r] = cvt(src[r*C + c]).
// ---------------------------------------------------------------------------
__global__ __launch_bounds__(256)
void transpose_cvt(const float* __restrict__ src, u16* __restrict__ dst, int R, int C) {
    __shared__ u16 tile[32][33];
    const int bx = blockIdx.x * 32, by = blockIdx.y * 32;
    const int tx = threadIdx.x & 31, ty = threadIdx.x >> 5;   // 32x8
    #pragma unroll
    for (int i = ty; i < 32; i += 8)
        tile[i][tx] = f2b(src[(size_t)(by + i) * C + bx + tx]);
    __syncthreads();
    #pragma unroll
    for (int i = ty; i < 32; i += 8) dst[(size_t)(bx + i) * R + by + tx] = tile[tx][i];
}

// ---------------------------------------------------------------------------
// TN MFMA GEMM: C[M,N] = A[M,K] * Bt[N,K]^T   (bf16 in, fp32 acc)
// 128x128 tile, BK=32, 4 waves 2x2, each 4x4 of 16x16x32 MFMA.
// Staging: __builtin_amdgcn_global_load_lds width=16 (m97 recipe) into
// UNPADDED 128x32 LDS tiles (global_load_lds dest = wave-uniform base +
// lane*16 -> layout must be lane-contiguous; b128 frag reads are bank-
// balanced at stride 64B: 256 words / 32 banks = 8 words/bank exactly).
// EPI: 1 = splitK fp32 partial, 2 = +bias then *qmul -> bf16, 0 = bf16.
// ---------------------------------------------------------------------------
template<int EPI>
__global__ __launch_bounds__(256)
void gemm_tn(const u16* __restrict__ A, const u16* __restrict__ Bt,
             int M, int N, int K, int kLen,
             float* __restrict__ Cf, u16* __restrict__ Cb,
             const float* __restrict__ bias, const float* __restrict__ qmul)
{
    __shared__ __align__(16) u16 lA[128 * 32];
    __shared__ __align__(16) u16 lB[128 * 32];

    const int t    = threadIdx.x;
    const int lane = t & 63;
    const int wave = t >> 6;
    const int wr = wave >> 1, wc = wave & 1;
    const int quad = lane >> 4, l16 = lane & 15;
    const int rowBase = blockIdx.y * 128;
    const int colBase = blockIdx.x * 128;
    const int k0 = blockIdx.z * kLen;

    // staging: wave w owns rows [w*32, w*32+32) of both tiles; 2 instrs of
    // 16 rows each. lane -> (row = base + lane/4, colChunk = lane%4).
    const u16* gA0 = A  + (size_t)(rowBase + wave * 32 + (lane >> 2)) * K + k0 + (lane & 3) * 8;
    const u16* gA1 = gA0 + 16 * (size_t)K;
    const u16* gB0 = Bt + (size_t)(colBase + wave * 32 + (lane >> 2)) * K + k0 + (lane & 3) * 8;
    const u16* gB1 = gB0 + 16 * (size_t)K;
    u16* sA0 = &lA[(wave * 32 +  0) * 32];
    u16* sA1 = &lA[(wave * 32 + 16) * 32];
    u16* sB0 = &lB[(wave * 32 +  0) * 32];
    u16* sB1 = &lB[(wave * 32 + 16) * 32];

    int afr[4], bfr[4];
    #pragma unroll
    for (int r = 0; r < 4; r++) afr[r] = (wr * 64 + r * 16 + l16) * 32 + quad * 8;
    #pragma unroll
    for (int c = 0; c < 4; c++) bfr[c] = (wc * 64 + c * 16 + l16) * 32 + quad * 8;

    f32x4 acc[4][4];
    #pragma unroll
    for (int r = 0; r < 4; r++)
        #pragma unroll
        for (int c = 0; c < 4; c++)
            acc[r][c] = (f32x4){0.f, 0.f, 0.f, 0.f};

    for (int kk = 0; kk < kLen; kk += 32) {
        __syncthreads();   // all waves done reading LDS from prior iter
        __builtin_amdgcn_global_load_lds(
            (const __attribute__((address_space(1))) void*)(gA0 + kk),
            (__attribute__((address_space(3))) void*)sA0, 16, 0, 0);
        __builtin_amdgcn_global_load_lds(
            (const __attribute__((address_space(1))) void*)(gA1 + kk),
            (__attribute__((address_space(3))) void*)sA1, 16, 0, 0);
        __builtin_amdgcn_global_load_lds(
            (const __attribute__((address_space(1))) void*)(gB0 + kk),
            (__attribute__((address_space(3))) void*)sB0, 16, 0, 0);
        __builtin_amdgcn_global_load_lds(
            (const __attribute__((address_space(1))) void*)(gB1 + kk),
            (__attribute__((address_space(3))) void*)sB1, 16, 0, 0);
        __syncthreads();   // compiler drains vmcnt(0) before barrier

        bf16x8 avf[4], bvf[4];
        #pragma unroll
        for (int r = 0; r < 4; r++) avf[r] = *(const bf16x8*)&lA[afr[r]];
        #pragma unroll
        for (int c = 0; c < 4; c++) bvf[c] = *(const bf16x8*)&lB[bfr[c]];
        #pragma unroll
        for (int r = 0; r < 4; r++)
            #pragma unroll
            for (int c = 0; c < 4; c++)
                acc[r][c] = __builtin_amdgcn_mfma_f32_16x16x32_bf16(avf[r], bvf[c], acc[r][c], 0, 0, 0);
    }

    // epilogue: D row = quad*4+reg, col = l16
    #pragma unroll
    for (int r = 0; r < 4; r++) {
        const int mBase = rowBase + wr * 64 + r * 16 + quad * 4;
        #pragma unroll
        for (int c = 0; c < 4; c++) {
            const int n = colBase + wc * 64 + c * 16 + l16;
            #pragma unroll
            for (int e = 0; e < 4; e++) {
                const int m = mBase + e;
                float v = acc[r][c][e];
                if (EPI == 1) {
                    Cf[((size_t)blockIdx.z * M + m) * N + n] = v;
                } else if (EPI == 2) {
                    v += bias[n];
                    v *= qmul[(size_t)(m / NOBJ) * N + n];
                    Cb[(size_t)m * N + n] = f2b(v);
                } else {
                    Cb[(size_t)m * N + n] = f2b(v);
                }
            }
        }
    }
}

// ---------------------------------------------------------------------------
__global__ __launch_bounds__(256)
void qcombine(const float* __restrict__ p, const float* __restrict__ bias,
              float* __restrict__ q, int MN, int S)
{
    const int i = blockIdx.x * 256 + threadIdx.x;
    float s = 0.f;
    for (int z = 0; z < S; z++) s += p[(size_t)z * MN + i];
    q[i] = s + bias[i & 2047];
}

// ---------------------------------------------------------------------------
// al_s / al_d: per (node, head) dot of h[n,hd,:] with a_src/a_dst (fp32).
// ---------------------------------------------------------------------------
template<int H, int C>
__global__ __launch_bounds__(H * 64)
void al_kernel(const u16* __restrict__ h, const float* __restrict__ a_s,
               const float* __restrict__ a_d, float* __restrict__ als, float* __restrict__ ald)
{
    const int n = blockIdx.x;
    const int wv = threadIdx.x >> 6, lane = threadIdx.x & 63;
    constexpr int PL = C / 64;
    const u16*   hp  = h   + (size_t)n * (H * C) + wv * C + lane * PL;
    const float* asp = a_s + wv * C + lane * PL;
    const float* adp = a_d + wv * C + lane * PL;
    u16 hb[PL];
    if constexpr (PL == 4) { *(uint2*)hb = *(const uint2*)hp; }
    else                   { *(uint4*)hb = *(const uint4*)hp; }
    float s1 = 0.f, s2 = 0.f;
    #pragma unroll
    for (int i = 0; i < PL; i++) {
        const float hv = b2f(hb[i]);
        s1 += hv * asp[i];
        s2 += hv * adp[i];
    }
    #pragma unroll
    for (int off = 32; off > 0; off >>= 1) {
        s1 += __shfl_down(s1, off);
        s2 += __shfl_down(s2, off);
    }
    if (lane == 0) { als[n * H + wv] = s1; ald[n * H + wv] = s2; }
}

// ---------------------------------------------------------------------------
// Attention + aggregate per (image, head).  MODE 1: relu(agg+b) -> g (bf16)
//                                           MODE 2: relu(agg+b)+resid -> g
// ---------------------------------------------------------------------------
template<int H, int C, int MODE>
__global__ __launch_bounds__(256)
void attn_kernel(const u16* __restrict__ h, const float* __restrict__ als,
                 const float* __restrict__ ald, const float* __restrict__ bias,
                 const u16* __restrict__ resid, u16* __restrict__ outb)
{
    __shared__ __align__(16) u16 hl[36 * C];
    __shared__ float alpha[36 * 36];
    __shared__ float asl[36], adl[36];
    const int b = blockIdx.y, hd = blockIdx.x;
    const int t = threadIdx.x;
    const int nb = b * NOBJ;
    if (t < 36) { asl[t] = als[(nb + t) * H + hd]; adl[t] = ald[(nb + t) * H + hd]; }
    constexpr int CH = C / 8;
    for (int e = t; e < 36 * CH; e += 256) {
        const int row = e / CH, col = (e - row * CH) * 8;
        *(uint4*)&hl[row * C + col] = *(const uint4*)&h[(size_t)(nb + row) * (H * C) + hd * C + col];
    }
    __syncthreads();
    if (t < 36) {
        const float ad = adl[t];
        float mx = -1e30f;
        for (int s = 0; s < 36; s++) {
            float v = asl[s] + ad; v = (v > 0.f) ? v : 0.2f * v;
            alpha[t * 36 + s] = v; mx = fmaxf(mx, v);
        }
        float sum = 0.f;
        for (int s = 0; s < 36; s++) { const float ex = expf(alpha[t * 36 + s] - mx); alpha[t * 36 + s] = ex; sum += ex; }
        const float inv = 1.f / (sum + 1e-16f);
        for (int s = 0; s < 36; s++) alpha[t * 36 + s] *= inv;
    }
    __syncthreads();
    constexpr int NC4 = C / 4;
    for (int e = t; e < 36 * NC4; e += 256) {
        const int d = e / NC4, c4 = (e - d * NC4) * 4;
        float a0 = 0, a1 = 0, a2 = 0, a3 = 0;
        for (int s = 0; s < 36; s++) {
            const float al = alpha[d * 36 + s];
            const ushort4 hv = *(const ushort4*)&hl[s * C + c4];
            a0 += al * b2f(hv.x); a1 += al * b2f(hv.y); a2 += al * b2f(hv.z); a3 += al * b2f(hv.w);
        }
        const int n = nb + d;
        const size_t base = (size_t)n * (H * C) + hd * C + c4;
        const int bb = hd * C + c4;
        float v0 = a0 + bias[bb + 0];
        float v1 = a1 + bias[bb + 1];
        float v2 = a2 + bias[bb + 2];
        float v3 = a3 + bias[bb + 3];
        v0 = v0 > 0.f ? v0 : 0.f; v1 = v1 > 0.f ? v1 : 0.f;
        v2 = v2 > 0.f ? v2 : 0.f; v3 = v3 > 0.f ? v3 : 0.f;
        if (MODE == 2) {
            v0 += b2f(resid[base + 0]); v1 += b2f(resid[base + 1]);
            v2 += b2f(resid[base + 2]); v3 += b2f(resid[base + 3]);
        }
        outb[base + 0] = f2b(v0); outb[base + 1] = f2b(v1);
        outb[base + 2] = f2b(v2); outb[base + 3] = f2b(v3);
    }
}

// ---------------------------------------------------------------------------
// Layer-3 attention: 5 heads, C=512, mean over heads + b3 -> fp32 d_out.
// ---------------------------------------------------------------------------
__global__ __launch_bounds__(256)
void attn_mean_kernel(const u16* __restrict__ h, const float* __restrict__ als,
                      const float* __restrict__ ald, const float* __restrict__ b3,
                      float* __restrict__ outp)
{
    __shared__ __align__(16) u16 hl[36 * 256];
    __shared__ float alpha[36 * 36];
    __shared__ float asl[36], adl[36];
    __shared__ float oacc[36 * 256];
    const int b = blockIdx.y, ch = blockIdx.x;
    const int t = threadIdx.x;
    const int nb = b * NOBJ, cbase = ch * 256;
    for (int e = t; e < 36 * 256; e += 256) oacc[e] = 0.f;
    for (int hd = 0; hd < 5; hd++) {
        __syncthreads();
        if (t < 36) { asl[t] = als[(nb + t) * 5 + hd]; adl[t] = ald[(nb + t) * 5 + hd]; }
        for (int e = t; e < 36 * 32; e += 256) {
            const int row = e >> 5, col = (e & 31) * 8;
            *(uint4*)&hl[row * 256 + col] = *(const uint4*)&h[(size_t)(nb + row) * 2560 + hd * 512 + cbase + col];
        }
        __syncthreads();
        if (t < 36) {
            const float ad = adl[t];
            float mx = -1e30f;
            for (int s = 0; s < 36; s++) {
                float v = asl[s] + ad; v = (v > 0.f) ? v : 0.2f * v;
                alpha[t * 36 + s] = v; mx = fmaxf(mx, v);
            }
            float sum = 0.f;
            for (int s = 0; s < 36; s++) { const float ex = expf(alpha[t * 36 + s] - mx); alpha[t * 36 + s] = ex; sum += ex; }
            const float inv = 1.f / (sum + 1e-16f);
            for (int s = 0; s < 36; s++) alpha[t * 36 + s] *= inv;
        }
        __syncthreads();
        for (int e = t; e < 36 * 64; e += 256) {
            const int d = e >> 6, c4 = (e & 63) * 4;
            float a0 = 0, a1 = 0, a2 = 0, a3 = 0;
            for (int s = 0; s < 36; s++) {
                const float al = alpha[d * 36 + s];
                const ushort4 hv = *(const ushort4*)&hl[s * 256 + c4];
                a0 += al * b2f(hv.x); a1 += al * b2f(hv.y); a2 += al * b2f(hv.z); a3 += al * b2f(hv.w);
            }
            oacc[d * 256 + c4 + 0] += a0; oacc[d * 256 + c4 + 1] += a1;
            oacc[d * 256 + c4 + 2] += a2; oacc[d * 256 + c4 + 3] += a3;
        }
    }
    __syncthreads();
    for (int e = t; e < 36 * 64; e += 256) {
        const int d = e >> 6, c4 = (e & 63) * 4;
        #pragma unroll
        for (int j = 0; j < 4; j++)
            outp[(size_t)(nb + d) * 512 + cbase + c4 + j] =
                oacc[d * 256 + c4 + j] * 0.2f + b3[cbase + c4 + j];
    }
}

// ---------------------------------------------------------------------------
// All inputs fp32, output fp32.  Workspace 62.1 MB (proven), lifetime-packed:
//  E: qe_c 0.59M | of_c 18.87M
//  A: WqT -> (qpart @ +9.83M) -> x -> g1 -> h3        (23.59M)
//  B: WvT | q(@ +8.39M) -> W1T -> W2T -> g2           ( 9.44M)
//  C: h1 -> h2 -> W3T                                 ( 9.44M)
//  D: als, ald
// ---------------------------------------------------------------------------
extern "C" void kernel_launch(void* const* d_in, const int* in_sizes, int n_in,
                              void* d_out, int out_size, void* d_ws, size_t ws_size,
                              hipStream_t stream)
{
    const float* qe  = (const float*)d_in[0];    // [128,2400]
    const float* of  = (const float*)d_in[1];    // [4608,2048]
    const float* Wq  = (const float*)d_in[3];    // [2400,2048]
    const float* bq  = (const float*)d_in[4];
    const float* Wv  = (const float*)d_in[5];    // [2048,2048]
    const float* bv  = (const float*)d_in[6];
    const float* W1  = (const float*)d_in[7];    // [2048,1024]
    const float* a1s = (const float*)d_in[8];
    const float* a1d = (const float*)d_in[9];
    const float* b1  = (const float*)d_in[10];
    const float* W2  = (const float*)d_in[11];   // [1024,1024]
    const float* a2s = (const float*)d_in[12];
    const float* a2d = (const float*)d_in[13];
    const float* b2  = (const float*)d_in[14];
    const float* W3  = (const float*)d_in[15];   // [1024,2560]
    const float* a3s = (const float*)d_in[16];
    const float* a3d = (const float*)d_in[17];
    const float* b3  = (const float*)d_in[18];
    float* out = (float*)d_out;
    (void)ws_size; (void)in_sizes; (void)n_in; (void)out_size;

    char* W0 = (char*)d_ws;
    size_t off = 0;
    auto alloc = [&](size_t bytes) -> char* {
        char* p = W0 + off; off += (bytes + 255) & ~(size_t)255; return p;
    };
    u16* qe_c = (u16*)alloc(128ull * 2400 * 2);
    u16* of_c = (u16*)alloc(4608ull * 2048 * 2);
    const size_t szA = 4608ull * 2560 * 2;
    const size_t szB = 4608ull * 1024 * 2;
    const size_t szC = 4608ull * 1024 * 2;
    char* Abase = alloc(szA);
    char* Bbase = alloc(szB);
    char* Cbase = alloc(szC);
    char* Dbase = alloc((size_t)NNODE * 5 * 4 * 2);

    u16*   WqT   = (u16*)Abase;                           // S1-S2
    float* qpart = (float*)(Abase + 2048ull * 2400 * 2);  // S2-S3
    u16*   x     = (u16*)Abase;                           // S5-S7
    u16*   g1    = (u16*)Abase;                           // S9-S13
    u16*   h3    = (u16*)Abase;                           // S15-S17
    u16*   WvT   = (u16*)Bbase;                           // S4-S5
    float* q     = (float*)(Bbase + 2048ull * 2048 * 2);  // S3-S5
    u16*   W1T   = (u16*)Bbase;                           // S6-S7
    u16*   W2T   = (u16*)Bbase;                           // S10-S11
    u16*   g2    = (u16*)Bbase;                           // S13-S15
    u16*   h1    = (u16*)Cbase;                           // S7-S9
    u16*   h2    = (u16*)Cbase;                           // S11-S13
    u16*   W3T   = (u16*)Cbase;                           // S14-S15
    float* als   = (float*)Dbase;
    float* ald   = (float*)(Dbase + (size_t)NNODE * 5 * 4);

    // S0: canonicalize activations to bf16
    conv_mat<<<(128 * 2400 / 4 + 255) / 256, 256, 0, stream>>>(qe, qe_c, 128 * 2400 / 4);
    conv_mat<<<(4608 * 2048 / 4 + 255) / 256, 256, 0, stream>>>(of, of_c, 4608 * 2048 / 4);

    // S1-S3: q = qe @ Wq + bq   (splitK=5, fp32 result)
    transpose_cvt<<<dim3(64, 75), 256, 0, stream>>>(Wq, WqT, 2400, 2048);
    gemm_tn<1><<<dim3(16, 1, 5), 256, 0, stream>>>(qe_c, WqT, 128, 2048, 2400, 480,
                                                   qpart, nullptr, nullptr, nullptr);
    qcombine<<<dim3(128 * 2048 / 256), 256, 0, stream>>>(qpart, bq, q, 128 * 2048, 5);

    // S4-S5: x = (of @ Wv + bv) * q_rep
    transpose_cvt<<<dim3(64, 64), 256, 0, stream>>>(Wv, WvT, 2048, 2048);
    gemm_tn<2><<<dim3(16, 36, 1), 256, 0, stream>>>(of_c, WvT, 4608, 2048, 2048, 2048,
                                                    nullptr, x, bv, q);

    // S6-S9: layer 1
    transpose_cvt<<<dim3(32, 64), 256, 0, stream>>>(W1, W1T, 2048, 1024);
    gemm_tn<0><<<dim3(8, 36, 1), 256, 0, stream>>>(x, W1T, 4608, 1024, 2048, 2048,
                                                   nullptr, h1, nullptr, nullptr);
    al_kernel<4, 256><<<dim3(NNODE), 256, 0, stream>>>(h1, a1s, a1d, als, ald);
    attn_kernel<4, 256, 1><<<dim3(4, B_IMG), 256, 0, stream>>>(h1, als, ald, b1, nullptr, g1);

    // S10-S13: layer 2 (+ residual g1)
    transpose_cvt<<<dim3(32, 32), 256, 0, stream>>>(W2, W2T, 1024, 1024);
    gemm_tn<0><<<dim3(8, 36, 1), 256, 0, stream>>>(g1, W2T, 4608, 1024, 1024, 1024,
                                                   nullptr, h2, nullptr, nullptr);
    al_kernel<4, 256><<<dim3(NNODE), 256, 0, stream>>>(h2, a2s, a2d, als, ald);
    attn_kernel<4, 256, 2><<<dim3(4, B_IMG), 256, 0, stream>>>(h2, als, ald, b2, g1, g2);

    // S14-S17: layer 3 (5 heads, mean + b3) -> fp32 out
    transpose_cvt<<<dim3(80, 32), 256, 0, stream>>>(W3, W3T, 1024, 2560);
    gemm_tn<0><<<dim3(20, 36, 1), 256, 0, stream>>>(g2, W3T, 4608, 2560, 1024, 1024,
                                                    nullptr, h3, nullptr, nullptr);
    al_kernel<5, 512><<<dim3(NNODE), 320, 0, stream>>>(h3, a3s, a3d, als, ald);
    attn_mean_kernel<<<dim3(2, B_IMG), 256, 0, stream>>>(h3, als, ald, b3, out);
}

// Round 6
// 482.936 us; speedup vs baseline: 1.1095x; 1.1095x over previous
//
#include <hip/hip_runtime.h>
#include <hip/hip_bf16.h>

typedef unsigned short u16;
typedef __bf16 bf16x8 __attribute__((ext_vector_type(8)));
typedef float f32x4 __attribute__((ext_vector_type(4)));

#define B_IMG 128
#define NOBJ  36
#define NNODE (B_IMG * NOBJ)

__device__ __forceinline__ float b2f(u16 u) {
    union { unsigned int i; float f; } v; v.i = ((unsigned int)u) << 16; return v.f;
}
__device__ __forceinline__ u16 f2b(float f) {
    union { float f; unsigned int i; } v; v.f = f;
    unsigned int u = v.i;
    return (u16)((u + 0x7fffu + ((u >> 16) & 1u)) >> 16);   // RNE
}

// ---------------------------------------------------------------------------
// fp32 -> bf16 packer. n4 = elems/4.
// ---------------------------------------------------------------------------
__global__ __launch_bounds__(256)
void conv_mat(const float* __restrict__ src, u16* __restrict__ dst, int n4) {
    const int i = blockIdx.x * 256 + threadIdx.x;
    if (i >= n4) return;
    const float4 f = ((const float4*)src)[i];
    ushort4 o; o.x = f2b(f.x); o.y = f2b(f.y); o.z = f2b(f.z); o.w = f2b(f.w);
    ((ushort4*)dst)[i] = o;
}

// ---------------------------------------------------------------------------
// fused fp32->bf16 convert + transpose: dst[c*R + r] = cvt(src[r*C + c]).
// ---------------------------------------------------------------------------
__global__ __launch_bounds__(256)
void transpose_cvt(const float* __restrict__ src, u16* __restrict__ dst, int R, int C) {
    __shared__ u16 tile[32][33];
    const int bx = blockIdx.x * 32, by = blockIdx.y * 32;
    const int tx = threadIdx.x & 31, ty = threadIdx.x >> 5;   // 32x8
    #pragma unroll
    for (int i = ty; i < 32; i += 8)
        tile[i][tx] = f2b(src[(size_t)(by + i) * C + bx + tx]);
    __syncthreads();
    #pragma unroll
    for (int i = ty; i < 32; i += 8) dst[(size_t)(bx + i) * R + by + tx] = tile[tx][i];
}

// ---------------------------------------------------------------------------
// TN MFMA GEMM: C[M,N] = A[M,K] * Bt[N,K]^T   (bf16 in, fp32 acc)
// 128x128 tile, BK=32, 4 waves 2x2, each 4x4 of 16x16x32 MFMA.
// Staging: global_load_lds width=16 into DOUBLE-BUFFERED unpadded 128x32
// tiles; DMA for tile k+1 issued BEFORE the MFMA section on tile k, so the
// vmcnt drain at the single per-iter barrier is overlapped by compute.
// (Round-5 serial DMA regressed: latency sat unoverlapped between 2 barriers.)
// EPI: 1 = splitK fp32 partial, 2 = +bias then *qmul -> bf16, 0 = bf16.
// ---------------------------------------------------------------------------
template<int EPI>
__global__ __launch_bounds__(256)
void gemm_tn(const u16* __restrict__ A, const u16* __restrict__ Bt,
             int M, int N, int K, int kLen,
             float* __restrict__ Cf, u16* __restrict__ Cb,
             const float* __restrict__ bias, const float* __restrict__ qmul)
{
    // [buf][tile]: A buffers at 0 / 4096, B buffers at 8192 / 12288 (u16 units)
    __shared__ __align__(16) u16 lds[4 * 128 * 32];

    const int t    = threadIdx.x;
    const int lane = t & 63;
    const int wave = t >> 6;
    const int wr = wave >> 1, wc = wave & 1;
    const int quad = lane >> 4, l16 = lane & 15;
    const int rowBase = blockIdx.y * 128;
    const int colBase = blockIdx.x * 128;
    const int k0 = blockIdx.z * kLen;

    // staging: wave w owns rows [w*32, w*32+32); 2 DMA of 16 rows each side.
    const u16* gA0 = A  + (size_t)(rowBase + wave * 32 + (lane >> 2)) * K + k0 + (lane & 3) * 8;
    const u16* gA1 = gA0 + 16 * (size_t)K;
    const u16* gB0 = Bt + (size_t)(colBase + wave * 32 + (lane >> 2)) * K + k0 + (lane & 3) * 8;
    const u16* gB1 = gB0 + 16 * (size_t)K;
    const int sA0 = (wave * 32 +  0) * 32;
    const int sA1 = (wave * 32 + 16) * 32;
    const int sB0 = 8192 + sA0;
    const int sB1 = 8192 + sA1;

    int afr[4], bfr[4];
    #pragma unroll
    for (int r = 0; r < 4; r++) afr[r] = (wr * 64 + r * 16 + l16) * 32 + quad * 8;
    #pragma unroll
    for (int c = 0; c < 4; c++) bfr[c] = 8192 + (wc * 64 + c * 16 + l16) * 32 + quad * 8;

    f32x4 acc[4][4];
    #pragma unroll
    for (int r = 0; r < 4; r++)
        #pragma unroll
        for (int c = 0; c < 4; c++)
            acc[r][c] = (f32x4){0.f, 0.f, 0.f, 0.f};

    auto dma_tile = [&](int kk, int buf) {
        const int bo = buf * 4096;
        __builtin_amdgcn_global_load_lds(
            (const __attribute__((address_space(1))) void*)(gA0 + kk),
            (__attribute__((address_space(3))) void*)&lds[sA0 + bo], 16, 0, 0);
        __builtin_amdgcn_global_load_lds(
            (const __attribute__((address_space(1))) void*)(gA1 + kk),
            (__attribute__((address_space(3))) void*)&lds[sA1 + bo], 16, 0, 0);
        __builtin_amdgcn_global_load_lds(
            (const __attribute__((address_space(1))) void*)(gB0 + kk),
            (__attribute__((address_space(3))) void*)&lds[sB0 + bo], 16, 0, 0);
        __builtin_amdgcn_global_load_lds(
            (const __attribute__((address_space(1))) void*)(gB1 + kk),
            (__attribute__((address_space(3))) void*)&lds[sB1 + bo], 16, 0, 0);
    };

    // prologue: tile 0 -> buf 0
    dma_tile(0, 0);
    __syncthreads();

    int cur = 0;
    for (int kk = 0; kk < kLen; kk += 32) {
        if (kk + 32 < kLen) dma_tile(kk + 32, cur ^ 1);   // in flight during MFMA

        const int bo = cur * 4096;
        bf16x8 avf[4], bvf[4];
        #pragma unroll
        for (int r = 0; r < 4; r++) avf[r] = *(const bf16x8*)&lds[afr[r] + bo];
        #pragma unroll
        for (int c = 0; c < 4; c++) bvf[c] = *(const bf16x8*)&lds[bfr[c] + bo];
        #pragma unroll
        for (int r = 0; r < 4; r++)
            #pragma unroll
            for (int c = 0; c < 4; c++)
                acc[r][c] = __builtin_amdgcn_mfma_f32_16x16x32_bf16(avf[r], bvf[c], acc[r][c], 0, 0, 0);

        __syncthreads();   // readers of buf[cur] done; DMA into buf[cur^1] drained
        cur ^= 1;
    }

    // epilogue: D row = quad*4+reg, col = l16
    #pragma unroll
    for (int r = 0; r < 4; r++) {
        const int mBase = rowBase + wr * 64 + r * 16 + quad * 4;
        #pragma unroll
        for (int c = 0; c < 4; c++) {
            const int n = colBase + wc * 64 + c * 16 + l16;
            #pragma unroll
            for (int e = 0; e < 4; e++) {
                const int m = mBase + e;
                float v = acc[r][c][e];
                if (EPI == 1) {
                    Cf[((size_t)blockIdx.z * M + m) * N + n] = v;
                } else if (EPI == 2) {
                    v += bias[n];
                    v *= qmul[(size_t)(m / NOBJ) * N + n];
                    Cb[(size_t)m * N + n] = f2b(v);
                } else {
                    Cb[(size_t)m * N + n] = f2b(v);
                }
            }
        }
    }
}

// ---------------------------------------------------------------------------
__global__ __launch_bounds__(256)
void qcombine(const float* __restrict__ p, const float* __restrict__ bias,
              float* __restrict__ q, int MN, int S)
{
    const int i = blockIdx.x * 256 + threadIdx.x;
    float s = 0.f;
    for (int z = 0; z < S; z++) s += p[(size_t)z * MN + i];
    q[i] = s + bias[i & 2047];
}

// ---------------------------------------------------------------------------
// al_s / al_d: per (node, head) dot of h[n,hd,:] with a_src/a_dst (fp32).
// ---------------------------------------------------------------------------
template<int H, int C>
__global__ __launch_bounds__(H * 64)
void al_kernel(const u16* __restrict__ h, const float* __restrict__ a_s,
               const float* __restrict__ a_d, float* __restrict__ als, float* __restrict__ ald)
{
    const int n = blockIdx.x;
    const int wv = threadIdx.x >> 6, lane = threadIdx.x & 63;
    constexpr int PL = C / 64;
    const u16*   hp  = h   + (size_t)n * (H * C) + wv * C + lane * PL;
    const float* asp = a_s + wv * C + lane * PL;
    const float* adp = a_d + wv * C + lane * PL;
    u16 hb[PL];
    if constexpr (PL == 4) { *(uint2*)hb = *(const uint2*)hp; }
    else                   { *(uint4*)hb = *(const uint4*)hp; }
    float s1 = 0.f, s2 = 0.f;
    #pragma unroll
    for (int i = 0; i < PL; i++) {
        const float hv = b2f(hb[i]);
        s1 += hv * asp[i];
        s2 += hv * adp[i];
    }
    #pragma unroll
    for (int off = 32; off > 0; off >>= 1) {
        s1 += __shfl_down(s1, off);
        s2 += __shfl_down(s2, off);
    }
    if (lane == 0) { als[n * H + wv] = s1; ald[n * H + wv] = s2; }
}

// ---------------------------------------------------------------------------
// Attention + aggregate per (image, head).  MODE 1: relu(agg+b) -> g (bf16)
//                                           MODE 2: relu(agg+b)+resid -> g
// ---------------------------------------------------------------------------
template<int H, int C, int MODE>
__global__ __launch_bounds__(256)
void attn_kernel(const u16* __restrict__ h, const float* __restrict__ als,
                 const float* __restrict__ ald, const float* __restrict__ bias,
                 const u16* __restrict__ resid, u16* __restrict__ outb)
{
    __shared__ __align__(16) u16 hl[36 * C];
    __shared__ float alpha[36 * 36];
    __shared__ float asl[36], adl[36];
    const int b = blockIdx.y, hd = blockIdx.x;
    const int t = threadIdx.x;
    const int nb = b * NOBJ;
    if (t < 36) { asl[t] = als[(nb + t) * H + hd]; adl[t] = ald[(nb + t) * H + hd]; }
    constexpr int CH = C / 8;
    for (int e = t; e < 36 * CH; e += 256) {
        const int row = e / CH, col = (e - row * CH) * 8;
        *(uint4*)&hl[row * C + col] = *(const uint4*)&h[(size_t)(nb + row) * (H * C) + hd * C + col];
    }
    __syncthreads();
    if (t < 36) {
        const float ad = adl[t];
        float mx = -1e30f;
        for (int s = 0; s < 36; s++) {
            float v = asl[s] + ad; v = (v > 0.f) ? v : 0.2f * v;
            alpha[t * 36 + s] = v; mx = fmaxf(mx, v);
        }
        float sum = 0.f;
        for (int s = 0; s < 36; s++) { const float ex = expf(alpha[t * 36 + s] - mx); alpha[t * 36 + s] = ex; sum += ex; }
        const float inv = 1.f / (sum + 1e-16f);
        for (int s = 0; s < 36; s++) alpha[t * 36 + s] *= inv;
    }
    __syncthreads();
    constexpr int NC4 = C / 4;
    for (int e = t; e < 36 * NC4; e += 256) {
        const int d = e / NC4, c4 = (e - d * NC4) * 4;
        float a0 = 0, a1 = 0, a2 = 0, a3 = 0;
        for (int s = 0; s < 36; s++) {
            const float al = alpha[d * 36 + s];
            const ushort4 hv = *(const ushort4*)&hl[s * C + c4];
            a0 += al * b2f(hv.x); a1 += al * b2f(hv.y); a2 += al * b2f(hv.z); a3 += al * b2f(hv.w);
        }
        const int n = nb + d;
        const size_t base = (size_t)n * (H * C) + hd * C + c4;
        const int bb = hd * C + c4;
        float v0 = a0 + bias[bb + 0];
        float v1 = a1 + bias[bb + 1];
        float v2 = a2 + bias[bb + 2];
        float v3 = a3 + bias[bb + 3];
        v0 = v0 > 0.f ? v0 : 0.f; v1 = v1 > 0.f ? v1 : 0.f;
        v2 = v2 > 0.f ? v2 : 0.f; v3 = v3 > 0.f ? v3 : 0.f;
        if (MODE == 2) {
            v0 += b2f(resid[base + 0]); v1 += b2f(resid[base + 1]);
            v2 += b2f(resid[base + 2]); v3 += b2f(resid[base + 3]);
        }
        outb[base + 0] = f2b(v0); outb[base + 1] = f2b(v1);
        outb[base + 2] = f2b(v2); outb[base + 3] = f2b(v3);
    }
}

// ---------------------------------------------------------------------------
// Layer-3 attention: 5 heads, C=512, mean over heads + b3 -> fp32 d_out.
// ---------------------------------------------------------------------------
__global__ __launch_bounds__(256)
void attn_mean_kernel(const u16* __restrict__ h, const float* __restrict__ als,
                      const float* __restrict__ ald, const float* __restrict__ b3,
                      float* __restrict__ outp)
{
    __shared__ __align__(16) u16 hl[36 * 256];
    __shared__ float alpha[36 * 36];
    __shared__ float asl[36], adl[36];
    __shared__ float oacc[36 * 256];
    const int b = blockIdx.y, ch = blockIdx.x;
    const int t = threadIdx.x;
    const int nb = b * NOBJ, cbase = ch * 256;
    for (int e = t; e < 36 * 256; e += 256) oacc[e] = 0.f;
    for (int hd = 0; hd < 5; hd++) {
        __syncthreads();
        if (t < 36) { asl[t] = als[(nb + t) * 5 + hd]; adl[t] = ald[(nb + t) * 5 + hd]; }
        for (int e = t; e < 36 * 32; e += 256) {
            const int row = e >> 5, col = (e & 31) * 8;
            *(uint4*)&hl[row * 256 + col] = *(const uint4*)&h[(size_t)(nb + row) * 2560 + hd * 512 + cbase + col];
        }
        __syncthreads();
        if (t < 36) {
            const float ad = adl[t];
            float mx = -1e30f;
            for (int s = 0; s < 36; s++) {
                float v = asl[s] + ad; v = (v > 0.f) ? v : 0.2f * v;
                alpha[t * 36 + s] = v; mx = fmaxf(mx, v);
            }
            float sum = 0.f;
            for (int s = 0; s < 36; s++) { const float ex = expf(alpha[t * 36 + s] - mx); alpha[t * 36 + s] = ex; sum += ex; }
            const float inv = 1.f / (sum + 1e-16f);
            for (int s = 0; s < 36; s++) alpha[t * 36 + s] *= inv;
        }
        __syncthreads();
        for (int e = t; e < 36 * 64; e += 256) {
            const int d = e >> 6, c4 = (e & 63) * 4;
            float a0 = 0, a1 = 0, a2 = 0, a3 = 0;
            for (int s = 0; s < 36; s++) {
                const float al = alpha[d * 36 + s];
                const ushort4 hv = *(const ushort4*)&hl[s * 256 + c4];
                a0 += al * b2f(hv.x); a1 += al * b2f(hv.y); a2 += al * b2f(hv.z); a3 += al * b2f(hv.w);
            }
            oacc[d * 256 + c4 + 0] += a0; oacc[d * 256 + c4 + 1] += a1;
            oacc[d * 256 + c4 + 2] += a2; oacc[d * 256 + c4 + 3] += a3;
        }
    }
    __syncthreads();
    for (int e = t; e < 36 * 64; e += 256) {
        const int d = e >> 6, c4 = (e & 63) * 4;
        #pragma unroll
        for (int j = 0; j < 4; j++)
            outp[(size_t)(nb + d) * 512 + cbase + c4 + j] =
                oacc[d * 256 + c4 + j] * 0.2f + b3[cbase + c4 + j];
    }
}

// ---------------------------------------------------------------------------
// All inputs fp32, output fp32.  Workspace 62.1 MB (proven), lifetime-packed:
//  E: qe_c 0.59M | of_c 18.87M
//  A: WqT -> (qpart @ +9.83M) -> x -> g1 -> h3        (23.59M)
//  B: WvT | q(@ +8.39M) -> W1T -> W2T -> g2           ( 9.44M)
//  C: h1 -> h2 -> W3T                                 ( 9.44M)
//  D: als, ald
// ---------------------------------------------------------------------------
extern "C" void kernel_launch(void* const* d_in, const int* in_sizes, int n_in,
                              void* d_out, int out_size, void* d_ws, size_t ws_size,
                              hipStream_t stream)
{
    const float* qe  = (const float*)d_in[0];    // [128,2400]
    const float* of  = (const float*)d_in[1];    // [4608,2048]
    const float* Wq  = (const float*)d_in[3];    // [2400,2048]
    const float* bq  = (const float*)d_in[4];
    const float* Wv  = (const float*)d_in[5];    // [2048,2048]
    const float* bv  = (const float*)d_in[6];
    const float* W1  = (const float*)d_in[7];    // [2048,1024]
    const float* a1s = (const float*)d_in[8];
    const float* a1d = (const float*)d_in[9];
    const float* b1  = (const float*)d_in[10];
    const float* W2  = (const float*)d_in[11];   // [1024,1024]
    const float* a2s = (const float*)d_in[12];
    const float* a2d = (const float*)d_in[13];
    const float* b2  = (const float*)d_in[14];
    const float* W3  = (const float*)d_in[15];   // [1024,2560]
    const float* a3s = (const float*)d_in[16];
    const float* a3d = (const float*)d_in[17];
    const float* b3  = (const float*)d_in[18];
    float* out = (float*)d_out;
    (void)ws_size; (void)in_sizes; (void)n_in; (void)out_size;

    char* W0 = (char*)d_ws;
    size_t off = 0;
    auto alloc = [&](size_t bytes) -> char* {
        char* p = W0 + off; off += (bytes + 255) & ~(size_t)255; return p;
    };
    u16* qe_c = (u16*)alloc(128ull * 2400 * 2);
    u16* of_c = (u16*)alloc(4608ull * 2048 * 2);
    const size_t szA = 4608ull * 2560 * 2;
    const size_t szB = 4608ull * 1024 * 2;
    const size_t szC = 4608ull * 1024 * 2;
    char* Abase = alloc(szA);
    char* Bbase = alloc(szB);
    char* Cbase = alloc(szC);
    char* Dbase = alloc((size_t)NNODE * 5 * 4 * 2);

    u16*   WqT   = (u16*)Abase;                           // S1-S2
    float* qpart = (float*)(Abase + 2048ull * 2400 * 2);  // S2-S3
    u16*   x     = (u16*)Abase;                           // S5-S7
    u16*   g1    = (u16*)Abase;                           // S9-S13
    u16*   h3    = (u16*)Abase;                           // S15-S17
    u16*   WvT   = (u16*)Bbase;                           // S4-S5
    float* q     = (float*)(Bbase + 2048ull * 2048 * 2);  // S3-S5
    u16*   W1T   = (u16*)Bbase;                           // S6-S7
    u16*   W2T   = (u16*)Bbase;                           // S10-S11
    u16*   g2    = (u16*)Bbase;                           // S13-S15
    u16*   h1    = (u16*)Cbase;                           // S7-S9
    u16*   h2    = (u16*)Cbase;                           // S11-S13
    u16*   W3T   = (u16*)Cbase;                           // S14-S15
    float* als   = (float*)Dbase;
    float* ald   = (float*)(Dbase + (size_t)NNODE * 5 * 4);

    // S0: canonicalize activations to bf16
    conv_mat<<<(128 * 2400 / 4 + 255) / 256, 256, 0, stream>>>(qe, qe_c, 128 * 2400 / 4);
    conv_mat<<<(4608 * 2048 / 4 + 255) / 256, 256, 0, stream>>>(of, of_c, 4608 * 2048 / 4);

    // S1-S3: q = qe @ Wq + bq   (splitK=5, fp32 result)
    transpose_cvt<<<dim3(64, 75), 256, 0, stream>>>(Wq, WqT, 2400, 2048);
    gemm_tn<1><<<dim3(16, 1, 5), 256, 0, stream>>>(qe_c, WqT, 128, 2048, 2400, 480,
                                                   qpart, nullptr, nullptr, nullptr);
    qcombine<<<dim3(128 * 2048 / 256), 256, 0, stream>>>(qpart, bq, q, 128 * 2048, 5);

    // S4-S5: x = (of @ Wv + bv) * q_rep
    transpose_cvt<<<dim3(64, 64), 256, 0, stream>>>(Wv, WvT, 2048, 2048);
    gemm_tn<2><<<dim3(16, 36, 1), 256, 0, stream>>>(of_c, WvT, 4608, 2048, 2048, 2048,
                                                    nullptr, x, bv, q);

    // S6-S9: layer 1
    transpose_cvt<<<dim3(32, 64), 256, 0, stream>>>(W1, W1T, 2048, 1024);
    gemm_tn<0><<<dim3(8, 36, 1), 256, 0, stream>>>(x, W1T, 4608, 1024, 2048, 2048,
                                                   nullptr, h1, nullptr, nullptr);
    al_kernel<4, 256><<<dim3(NNODE), 256, 0, stream>>>(h1, a1s, a1d, als, ald);
    attn_kernel<4, 256, 1><<<dim3(4, B_IMG), 256, 0, stream>>>(h1, als, ald, b1, nullptr, g1);

    // S10-S13: layer 2 (+ residual g1)
    transpose_cvt<<<dim3(32, 32), 256, 0, stream>>>(W2, W2T, 1024, 1024);
    gemm_tn<0><<<dim3(8, 36, 1), 256, 0, stream>>>(g1, W2T, 4608, 1024, 1024, 1024,
                                                   nullptr, h2, nullptr, nullptr);
    al_kernel<4, 256><<<dim3(NNODE), 256, 0, stream>>>(h2, a2s, a2d, als, ald);
    attn_kernel<4, 256, 2><<<dim3(4, B_IMG), 256, 0, stream>>>(h2, als, ald, b2, g1, g2);

    // S14-S17: layer 3 (5 heads, mean + b3) -> fp32 out
    transpose_cvt<<<dim3(80, 32), 256, 0, stream>>>(W3, W3T, 1024, 2560);
    gemm_tn<0><<<dim3(20, 36, 1), 256, 0, stream>>>(g2, W3T, 4608, 2560, 1024, 1024,
                                                    nullptr, h3, nullptr, nullptr);
    al_kernel<5, 512><<<dim3(NNODE), 320, 0, stream>>>(h3, a3s, a3d, als, ald);
    attn_mean_kernel<<<dim3(2, B_IMG), 256, 0, stream>>>(h3, als, ald, b3, out);
}

// Round 7
// 474.938 us; speedup vs baseline: 1.1282x; 1.0168x over previous
//
#include <hip/hip_runtime.h>
#include <hip/hip_bf16.h>

typedef unsigned short u16;
typedef __bf16 bf16x8 __attribute__((ext_vector_type(8)));
typedef float f32x4 __attribute__((ext_vector_type(4)));

#define B_IMG 128
#define NOBJ  36
#define NNODE (B_IMG * NOBJ)

__device__ __forceinline__ float b2f(u16 u) {
    union { unsigned int i; float f; } v; v.i = ((unsigned int)u) << 16; return v.f;
}
__device__ __forceinline__ u16 f2b(float f) {
    union { float f; unsigned int i; } v; v.f = f;
    unsigned int u = v.i;
    return (u16)((u + 0x7fffu + ((u >> 16) & 1u)) >> 16);   // RNE
}

// ---------------------------------------------------------------------------
// fp32 -> bf16 packer. n4 = elems/4.
// ---------------------------------------------------------------------------
__global__ __launch_bounds__(256)
void conv_mat(const float* __restrict__ src, u16* __restrict__ dst, int n4) {
    const int i = blockIdx.x * 256 + threadIdx.x;
    if (i >= n4) return;
    const float4 f = ((const float4*)src)[i];
    ushort4 o; o.x = f2b(f.x); o.y = f2b(f.y); o.z = f2b(f.z); o.w = f2b(f.w);
    ((ushort4*)dst)[i] = o;
}

// ---------------------------------------------------------------------------
// fused fp32->bf16 convert + transpose: dst[c*R + r] = cvt(src[r*C + c]).
// ---------------------------------------------------------------------------
__global__ __launch_bounds__(256)
void transpose_cvt(const float* __restrict__ src, u16* __restrict__ dst, int R, int C) {
    __shared__ u16 tile[32][33];
    const int bx = blockIdx.x * 32, by = blockIdx.y * 32;
    const int tx = threadIdx.x & 31, ty = threadIdx.x >> 5;   // 32x8
    #pragma unroll
    for (int i = ty; i < 32; i += 8)
        tile[i][tx] = f2b(src[(size_t)(by + i) * C + bx + tx]);
    __syncthreads();
    #pragma unroll
    for (int i = ty; i < 32; i += 8) dst[(size_t)(bx + i) * R + by + tx] = tile[tx][i];
}

// ---------------------------------------------------------------------------
// TN MFMA GEMM: C[M,N] = A[M,K] * Bt[N,K]^T   (bf16 in, fp32 acc)
// 128x128 tile, BK=32, 4 waves 2x2, each 4x4 of 16x16x32 MFMA.
// K-loop: AITER-style 3-stage LDS pipeline with global_load_lds width=16,
// ONE raw s_barrier per iter and fine-grained s_waitcnt vmcnt(4) (never 0
// until the last tile) so prefetch DMAs stay in flight across the barrier.
// Safety: vmcnt(4) leaves only tile it+1 pending per wave => tile it landed
// for all waves after the barrier; DMA target stage (cur+2)%3 was last READ
// at iter it-1 and those ds_reads are ordered before the post-barrier DMA by
// the memory-clobbered asm barrier.
// EPI: 1 = splitK fp32 partial, 2 = +bias then *qmul -> bf16, 0 = bf16.
// ---------------------------------------------------------------------------
template<int EPI>
__global__ __launch_bounds__(256)
void gemm_tn(const u16* __restrict__ A, const u16* __restrict__ Bt,
             int M, int N, int K, int kLen,
             float* __restrict__ Cf, u16* __restrict__ Cb,
             const float* __restrict__ bias, const float* __restrict__ qmul)
{
    // 3 stages x (A 4096 + B 4096) u16 = 48 KB
    __shared__ __align__(16) u16 lds[3 * 8192];

    const int t    = threadIdx.x;
    const int lane = t & 63;
    const int wave = t >> 6;
    const int wr = wave >> 1, wc = wave & 1;
    const int quad = lane >> 4, l16 = lane & 15;
    const int rowBase = blockIdx.y * 128;
    const int colBase = blockIdx.x * 128;
    const int k0 = blockIdx.z * kLen;

    // staging: wave w owns rows [w*32, w*32+32); 2 DMA of 16 rows per matrix.
    const u16* gA0 = A  + (size_t)(rowBase + wave * 32 + (lane >> 2)) * K + k0 + (lane & 3) * 8;
    const u16* gA1 = gA0 + 16 * (size_t)K;
    const u16* gB0 = Bt + (size_t)(colBase + wave * 32 + (lane >> 2)) * K + k0 + (lane & 3) * 8;
    const u16* gB1 = gB0 + 16 * (size_t)K;
    const int sO0 = (wave * 32 +  0) * 32;
    const int sO1 = (wave * 32 + 16) * 32;

    int afr[4], bfr[4];
    #pragma unroll
    for (int r = 0; r < 4; r++) afr[r] = (wr * 64 + r * 16 + l16) * 32 + quad * 8;
    #pragma unroll
    for (int c = 0; c < 4; c++) bfr[c] = 4096 + (wc * 64 + c * 16 + l16) * 32 + quad * 8;

    f32x4 acc[4][4];
    #pragma unroll
    for (int r = 0; r < 4; r++)
        #pragma unroll
        for (int c = 0; c < 4; c++)
            acc[r][c] = (f32x4){0.f, 0.f, 0.f, 0.f};

    auto dma_tile = [&](int it, int st) {
        const int kk = it * 32;
        const int bo = st * 8192;
        __builtin_amdgcn_global_load_lds(
            (const __attribute__((address_space(1))) void*)(gA0 + kk),
            (__attribute__((address_space(3))) void*)&lds[bo + sO0], 16, 0, 0);
        __builtin_amdgcn_global_load_lds(
            (const __attribute__((address_space(1))) void*)(gA1 + kk),
            (__attribute__((address_space(3))) void*)&lds[bo + sO1], 16, 0, 0);
        __builtin_amdgcn_global_load_lds(
            (const __attribute__((address_space(1))) void*)(gB0 + kk),
            (__attribute__((address_space(3))) void*)&lds[bo + 4096 + sO0], 16, 0, 0);
        __builtin_amdgcn_global_load_lds(
            (const __attribute__((address_space(1))) void*)(gB1 + kk),
            (__attribute__((address_space(3))) void*)&lds[bo + 4096 + sO1], 16, 0, 0);
    };

    const int nIter = kLen >> 5;   // >= 15 for all our shapes
    dma_tile(0, 0);
    dma_tile(1, 1);

    int cur = 0;
    for (int it = 0; it < nIter; ++it) {
        if (it + 1 < nIter) {
            asm volatile("s_waitcnt vmcnt(4)\n\ts_barrier" ::: "memory");
        } else {
            asm volatile("s_waitcnt vmcnt(0)\n\ts_barrier" ::: "memory");
        }
        if (it + 2 < nIter) {
            const int st2 = (cur + 2 >= 3) ? cur - 1 : cur + 2;
            dma_tile(it + 2, st2);
        }
        const int bo = cur * 8192;
        bf16x8 avf[4], bvf[4];
        #pragma unroll
        for (int r = 0; r < 4; r++) avf[r] = *(const bf16x8*)&lds[afr[r] + bo];
        #pragma unroll
        for (int c = 0; c < 4; c++) bvf[c] = *(const bf16x8*)&lds[bfr[c] + bo];
        #pragma unroll
        for (int r = 0; r < 4; r++)
            #pragma unroll
            for (int c = 0; c < 4; c++)
                acc[r][c] = __builtin_amdgcn_mfma_f32_16x16x32_bf16(avf[r], bvf[c], acc[r][c], 0, 0, 0);
        cur = (cur + 1 == 3) ? 0 : cur + 1;
    }

    // epilogue: D row = quad*4+reg, col = l16
    #pragma unroll
    for (int r = 0; r < 4; r++) {
        const int mBase = rowBase + wr * 64 + r * 16 + quad * 4;
        #pragma unroll
        for (int c = 0; c < 4; c++) {
            const int n = colBase + wc * 64 + c * 16 + l16;
            #pragma unroll
            for (int e = 0; e < 4; e++) {
                const int m = mBase + e;
                float v = acc[r][c][e];
                if (EPI == 1) {
                    Cf[((size_t)blockIdx.z * M + m) * N + n] = v;
                } else if (EPI == 2) {
                    v += bias[n];
                    v *= qmul[(size_t)(m / NOBJ) * N + n];
                    Cb[(size_t)m * N + n] = f2b(v);
                } else {
                    Cb[(size_t)m * N + n] = f2b(v);
                }
            }
        }
    }
}

// ---------------------------------------------------------------------------
__global__ __launch_bounds__(256)
void qcombine(const float* __restrict__ p, const float* __restrict__ bias,
              float* __restrict__ q, int MN, int S)
{
    const int i = blockIdx.x * 256 + threadIdx.x;
    float s = 0.f;
    for (int z = 0; z < S; z++) s += p[(size_t)z * MN + i];
    q[i] = s + bias[i & 2047];
}

// ---------------------------------------------------------------------------
// al_s / al_d (layer-3 only): per (node, head) dot of h[n,hd,:] with a vecs.
// ---------------------------------------------------------------------------
template<int H, int C>
__global__ __launch_bounds__(H * 64)
void al_kernel(const u16* __restrict__ h, const float* __restrict__ a_s,
               const float* __restrict__ a_d, float* __restrict__ als, float* __restrict__ ald)
{
    const int n = blockIdx.x;
    const int wv = threadIdx.x >> 6, lane = threadIdx.x & 63;
    constexpr int PL = C / 64;
    const u16*   hp  = h   + (size_t)n * (H * C) + wv * C + lane * PL;
    const float* asp = a_s + wv * C + lane * PL;
    const float* adp = a_d + wv * C + lane * PL;
    u16 hb[PL];
    if constexpr (PL == 4) { *(uint2*)hb = *(const uint2*)hp; }
    else                   { *(uint4*)hb = *(const uint4*)hp; }
    float s1 = 0.f, s2 = 0.f;
    #pragma unroll
    for (int i = 0; i < PL; i++) {
        const float hv = b2f(hb[i]);
        s1 += hv * asp[i];
        s2 += hv * adp[i];
    }
    #pragma unroll
    for (int off = 32; off > 0; off >>= 1) {
        s1 += __shfl_down(s1, off);
        s2 += __shfl_down(s2, off);
    }
    if (lane == 0) { als[n * H + wv] = s1; ald[n * H + wv] = s2; }
}

// ---------------------------------------------------------------------------
// Attention + aggregate per (image, head), WITH FUSED al computation (the
// h-tile is already in LDS).  MODE 1: relu(agg+b) -> g (bf16)
//                             MODE 2: relu(agg+b)+resid -> g
// ---------------------------------------------------------------------------
template<int H, int C, int MODE>
__global__ __launch_bounds__(256)
void attn_kernel(const u16* __restrict__ h, const float* __restrict__ a_src,
                 const float* __restrict__ a_dst, const float* __restrict__ bias,
                 const u16* __restrict__ resid, u16* __restrict__ outb)
{
    __shared__ __align__(16) u16 hl[36 * C];
    __shared__ float alpha[36 * 36];
    __shared__ float asl[36], adl[36];
    __shared__ float psum[36][8][2];
    const int b = blockIdx.y, hd = blockIdx.x;
    const int t = threadIdx.x;
    const int nb = b * NOBJ;
    constexpr int CH = C / 8;
    for (int e = t; e < 36 * CH; e += 256) {
        const int row = e / CH, col = (e - row * CH) * 8;
        *(uint4*)&hl[row * C + col] = *(const uint4*)&h[(size_t)(nb + row) * (H * C) + hd * C + col];
    }
    __syncthreads();
    // fused al: partial dots over 8 segments per node
    constexpr int SEG = C / 8;
    for (int e = t; e < 36 * 8; e += 256) {
        const int n = e >> 3, sg = e & 7;
        const u16*   hp = &hl[n * C + sg * SEG];
        const float* as = a_src + hd * C + sg * SEG;
        const float* ad = a_dst + hd * C + sg * SEG;
        float s1 = 0.f, s2 = 0.f;
        #pragma unroll 8
        for (int i = 0; i < SEG; i++) {
            const float hv = b2f(hp[i]);
            s1 += hv * as[i]; s2 += hv * ad[i];
        }
        psum[n][sg][0] = s1; psum[n][sg][1] = s2;
    }
    __syncthreads();
    if (t < 36) {
        float s1 = 0.f, s2 = 0.f;
        #pragma unroll
        for (int sg = 0; sg < 8; sg++) { s1 += psum[t][sg][0]; s2 += psum[t][sg][1]; }
        asl[t] = s1; adl[t] = s2;
    }
    __syncthreads();
    if (t < 36) {   // softmax over sources for destination d = t
        const float ad = adl[t];
        float mx = -1e30f;
        for (int s = 0; s < 36; s++) {
            float v = asl[s] + ad; v = (v > 0.f) ? v : 0.2f * v;
            alpha[t * 36 + s] = v; mx = fmaxf(mx, v);
        }
        float sum = 0.f;
        for (int s = 0; s < 36; s++) { const float ex = expf(alpha[t * 36 + s] - mx); alpha[t * 36 + s] = ex; sum += ex; }
        const float inv = 1.f / (sum + 1e-16f);
        for (int s = 0; s < 36; s++) alpha[t * 36 + s] *= inv;
    }
    __syncthreads();
    constexpr int NC4 = C / 4;
    for (int e = t; e < 36 * NC4; e += 256) {
        const int d = e / NC4, c4 = (e - d * NC4) * 4;
        float a0 = 0, a1 = 0, a2 = 0, a3 = 0;
        for (int s = 0; s < 36; s++) {
            const float al = alpha[d * 36 + s];
            const ushort4 hv = *(const ushort4*)&hl[s * C + c4];
            a0 += al * b2f(hv.x); a1 += al * b2f(hv.y); a2 += al * b2f(hv.z); a3 += al * b2f(hv.w);
        }
        const int n = nb + d;
        const size_t base = (size_t)n * (H * C) + hd * C + c4;
        const int bb = hd * C + c4;
        float v0 = a0 + bias[bb + 0];
        float v1 = a1 + bias[bb + 1];
        float v2 = a2 + bias[bb + 2];
        float v3 = a3 + bias[bb + 3];
        v0 = v0 > 0.f ? v0 : 0.f; v1 = v1 > 0.f ? v1 : 0.f;
        v2 = v2 > 0.f ? v2 : 0.f; v3 = v3 > 0.f ? v3 : 0.f;
        if (MODE == 2) {
            v0 += b2f(resid[base + 0]); v1 += b2f(resid[base + 1]);
            v2 += b2f(resid[base + 2]); v3 += b2f(resid[base + 3]);
        }
        outb[base + 0] = f2b(v0); outb[base + 1] = f2b(v1);
        outb[base + 2] = f2b(v2); outb[base + 3] = f2b(v3);
    }
}

// ---------------------------------------------------------------------------
// Layer-3 attention: 5 heads, C=512, mean over heads + b3 -> fp32 d_out.
// ---------------------------------------------------------------------------
__global__ __launch_bounds__(256)
void attn_mean_kernel(const u16* __restrict__ h, const float* __restrict__ als,
                      const float* __restrict__ ald, const float* __restrict__ b3,
                      float* __restrict__ outp)
{
    __shared__ __align__(16) u16 hl[36 * 256];
    __shared__ float alpha[36 * 36];
    __shared__ float asl[36], adl[36];
    __shared__ float oacc[36 * 256];
    const int b = blockIdx.y, ch = blockIdx.x;
    const int t = threadIdx.x;
    const int nb = b * NOBJ, cbase = ch * 256;
    for (int e = t; e < 36 * 256; e += 256) oacc[e] = 0.f;
    for (int hd = 0; hd < 5; hd++) {
        __syncthreads();
        if (t < 36) { asl[t] = als[(nb + t) * 5 + hd]; adl[t] = ald[(nb + t) * 5 + hd]; }
        for (int e = t; e < 36 * 32; e += 256) {
            const int row = e >> 5, col = (e & 31) * 8;
            *(uint4*)&hl[row * 256 + col] = *(const uint4*)&h[(size_t)(nb + row) * 2560 + hd * 512 + cbase + col];
        }
        __syncthreads();
        if (t < 36) {
            const float ad = adl[t];
            float mx = -1e30f;
            for (int s = 0; s < 36; s++) {
                float v = asl[s] + ad; v = (v > 0.f) ? v : 0.2f * v;
                alpha[t * 36 + s] = v; mx = fmaxf(mx, v);
            }
            float sum = 0.f;
            for (int s = 0; s < 36; s++) { const float ex = expf(alpha[t * 36 + s] - mx); alpha[t * 36 + s] = ex; sum += ex; }
            const float inv = 1.f / (sum + 1e-16f);
            for (int s = 0; s < 36; s++) alpha[t * 36 + s] *= inv;
        }
        __syncthreads();
        for (int e = t; e < 36 * 64; e += 256) {
            const int d = e >> 6, c4 = (e & 63) * 4;
            float a0 = 0, a1 = 0, a2 = 0, a3 = 0;
            for (int s = 0; s < 36; s++) {
                const float al = alpha[d * 36 + s];
                const ushort4 hv = *(const ushort4*)&hl[s * 256 + c4];
                a0 += al * b2f(hv.x); a1 += al * b2f(hv.y); a2 += al * b2f(hv.z); a3 += al * b2f(hv.w);
            }
            oacc[d * 256 + c4 + 0] += a0; oacc[d * 256 + c4 + 1] += a1;
            oacc[d * 256 + c4 + 2] += a2; oacc[d * 256 + c4 + 3] += a3;
        }
    }
    __syncthreads();
    for (int e = t; e < 36 * 64; e += 256) {
        const int d = e >> 6, c4 = (e & 63) * 4;
        #pragma unroll
        for (int j = 0; j < 4; j++)
            outp[(size_t)(nb + d) * 512 + cbase + c4 + j] =
                oacc[d * 256 + c4 + j] * 0.2f + b3[cbase + c4 + j];
    }
}

// ---------------------------------------------------------------------------
// All inputs fp32, output fp32.  Workspace 62.1 MB, lifetime-packed:
//  E: qe_c 0.59M | of_c 18.87M
//  A: WqT -> (qpart @ +9.83M) -> x -> g1 -> h3        (23.59M)
//  B: WvT | q(@ +8.39M) -> W1T -> W2T -> g2           ( 9.44M)
//  C: h1 -> h2 -> W3T                                 ( 9.44M)
//  D: als, ald
// ---------------------------------------------------------------------------
extern "C" void kernel_launch(void* const* d_in, const int* in_sizes, int n_in,
                              void* d_out, int out_size, void* d_ws, size_t ws_size,
                              hipStream_t stream)
{
    const float* qe  = (const float*)d_in[0];    // [128,2400]
    const float* of  = (const float*)d_in[1];    // [4608,2048]
    const float* Wq  = (const float*)d_in[3];    // [2400,2048]
    const float* bq  = (const float*)d_in[4];
    const float* Wv  = (const float*)d_in[5];    // [2048,2048]
    const float* bv  = (const float*)d_in[6];
    const float* W1  = (const float*)d_in[7];    // [2048,1024]
    const float* a1s = (const float*)d_in[8];
    const float* a1d = (const float*)d_in[9];
    const float* b1  = (const float*)d_in[10];
    const float* W2  = (const float*)d_in[11];   // [1024,1024]
    const float* a2s = (const float*)d_in[12];
    const float* a2d = (const float*)d_in[13];
    const float* b2  = (const float*)d_in[14];
    const float* W3  = (const float*)d_in[15];   // [1024,2560]
    const float* a3s = (const float*)d_in[16];
    const float* a3d = (const float*)d_in[17];
    const float* b3  = (const float*)d_in[18];
    float* out = (float*)d_out;
    (void)ws_size; (void)in_sizes; (void)n_in; (void)out_size;

    char* W0 = (char*)d_ws;
    size_t off = 0;
    auto alloc = [&](size_t bytes) -> char* {
        char* p = W0 + off; off += (bytes + 255) & ~(size_t)255; return p;
    };
    u16* qe_c = (u16*)alloc(128ull * 2400 * 2);
    u16* of_c = (u16*)alloc(4608ull * 2048 * 2);
    const size_t szA = 4608ull * 2560 * 2;
    const size_t szB = 4608ull * 1024 * 2;
    const size_t szC = 4608ull * 1024 * 2;
    char* Abase = alloc(szA);
    char* Bbase = alloc(szB);
    char* Cbase = alloc(szC);
    char* Dbase = alloc((size_t)NNODE * 5 * 4 * 2);

    u16*   WqT   = (u16*)Abase;                           // S1-S2
    float* qpart = (float*)(Abase + 2048ull * 2400 * 2);  // S2-S3
    u16*   x     = (u16*)Abase;                           // S5-S7
    u16*   g1    = (u16*)Abase;                           // S9-S13
    u16*   h3    = (u16*)Abase;                           // S15-S17
    u16*   WvT   = (u16*)Bbase;                           // S4-S5
    float* q     = (float*)(Bbase + 2048ull * 2048 * 2);  // S3-S5
    u16*   W1T   = (u16*)Bbase;                           // S6-S7
    u16*   W2T   = (u16*)Bbase;                           // S10-S11
    u16*   g2    = (u16*)Bbase;                           // S13-S15
    u16*   h1    = (u16*)Cbase;                           // S7-S9
    u16*   h2    = (u16*)Cbase;                           // S11-S13
    u16*   W3T   = (u16*)Cbase;                           // S14-S15
    float* als   = (float*)Dbase;
    float* ald   = (float*)(Dbase + (size_t)NNODE * 5 * 4);

    // S0: canonicalize activations to bf16
    conv_mat<<<(128 * 2400 / 4 + 255) / 256, 256, 0, stream>>>(qe, qe_c, 128 * 2400 / 4);
    conv_mat<<<(4608 * 2048 / 4 + 255) / 256, 256, 0, stream>>>(of, of_c, 4608 * 2048 / 4);

    // S1-S3: q = qe @ Wq + bq   (splitK=5, fp32 result)
    transpose_cvt<<<dim3(64, 75), 256, 0, stream>>>(Wq, WqT, 2400, 2048);
    gemm_tn<1><<<dim3(16, 1, 5), 256, 0, stream>>>(qe_c, WqT, 128, 2048, 2400, 480,
                                                   qpart, nullptr, nullptr, nullptr);
    qcombine<<<dim3(128 * 2048 / 256), 256, 0, stream>>>(qpart, bq, q, 128 * 2048, 5);

    // S4-S5: x = (of @ Wv + bv) * q_rep
    transpose_cvt<<<dim3(64, 64), 256, 0, stream>>>(Wv, WvT, 2048, 2048);
    gemm_tn<2><<<dim3(16, 36, 1), 256, 0, stream>>>(of_c, WvT, 4608, 2048, 2048, 2048,
                                                    nullptr, x, bv, q);

    // S6-S9: layer 1 (al fused into attn)
    transpose_cvt<<<dim3(32, 64), 256, 0, stream>>>(W1, W1T, 2048, 1024);
    gemm_tn<0><<<dim3(8, 36, 1), 256, 0, stream>>>(x, W1T, 4608, 1024, 2048, 2048,
                                                   nullptr, h1, nullptr, nullptr);
    attn_kernel<4, 256, 1><<<dim3(4, B_IMG), 256, 0, stream>>>(h1, a1s, a1d, b1, nullptr, g1);

    // S10-S13: layer 2 (+ residual g1, al fused)
    transpose_cvt<<<dim3(32, 32), 256, 0, stream>>>(W2, W2T, 1024, 1024);
    gemm_tn<0><<<dim3(8, 36, 1), 256, 0, stream>>>(g1, W2T, 4608, 1024, 1024, 1024,
                                                   nullptr, h2, nullptr, nullptr);
    attn_kernel<4, 256, 2><<<dim3(4, B_IMG), 256, 0, stream>>>(h2, a2s, a2d, b2, g1, g2);

    // S14-S17: layer 3 (5 heads, mean + b3) -> fp32 out
    transpose_cvt<<<dim3(80, 32), 256, 0, stream>>>(W3, W3T, 1024, 2560);
    gemm_tn<0><<<dim3(20, 36, 1), 256, 0, stream>>>(g2, W3T, 4608, 2560, 1024, 1024,
                                                    nullptr, h3, nullptr, nullptr);
    al_kernel<5, 512><<<dim3(NNODE), 320, 0, stream>>>(h3, a3s, a3d, als, ald);
    attn_mean_kernel<<<dim3(2, B_IMG), 256, 0, stream>>>(h3, als, ald, b3, out);
}

// Round 8
// 453.683 us; speedup vs baseline: 1.1810x; 1.0468x over previous
//
#include <hip/hip_runtime.h>
#include <hip/hip_bf16.h>

typedef unsigned short u16;
typedef __bf16 bf16x8 __attribute__((ext_vector_type(8)));
typedef float f32x4 __attribute__((ext_vector_type(4)));

#define B_IMG 128
#define NOBJ  36
#define NNODE (B_IMG * NOBJ)

__device__ __forceinline__ float b2f(u16 u) {
    union { unsigned int i; float f; } v; v.i = ((unsigned int)u) << 16; return v.f;
}
__device__ __forceinline__ u16 f2b(float f) {
    union { float f; unsigned int i; } v; v.f = f;
    unsigned int u = v.i;
    return (u16)((u + 0x7fffu + ((u >> 16) & 1u)) >> 16);   // RNE
}

// ---------------------------------------------------------------------------
// fp32 -> bf16 packer. n4 = elems/4.
// ---------------------------------------------------------------------------
__global__ __launch_bounds__(256)
void conv_mat(const float* __restrict__ src, u16* __restrict__ dst, int n4) {
    const int i = blockIdx.x * 256 + threadIdx.x;
    if (i >= n4) return;
    const float4 f = ((const float4*)src)[i];
    ushort4 o; o.x = f2b(f.x); o.y = f2b(f.y); o.z = f2b(f.z); o.w = f2b(f.w);
    ((ushort4*)dst)[i] = o;
}

// ---------------------------------------------------------------------------
// qe pad-convert: [128,2400] fp32 -> [128,2560] bf16, zero pad cols >= 2400.
// ---------------------------------------------------------------------------
__global__ __launch_bounds__(256)
void conv_pad_qe(const float* __restrict__ src, u16* __restrict__ dst) {
    const int i = blockIdx.x * 256 + threadIdx.x;
    if (i >= 128 * 2560) return;
    const int r = i / 2560, c = i - r * 2560;
    dst[i] = (c < 2400) ? f2b(src[r * 2400 + c]) : (u16)0;
}

// ---------------------------------------------------------------------------
// fused fp32->bf16 convert + transpose: dst[c*R + r] = cvt(src[r*C + c]).
// ---------------------------------------------------------------------------
__global__ __launch_bounds__(256)
void transpose_cvt(const float* __restrict__ src, u16* __restrict__ dst, int R, int C) {
    __shared__ u16 tile[32][33];
    const int bx = blockIdx.x * 32, by = blockIdx.y * 32;
    const int tx = threadIdx.x & 31, ty = threadIdx.x >> 5;   // 32x8
    #pragma unroll
    for (int i = ty; i < 32; i += 8)
        tile[i][tx] = f2b(src[(size_t)(by + i) * C + bx + tx]);
    __syncthreads();
    #pragma unroll
    for (int i = ty; i < 32; i += 8) dst[(size_t)(bx + i) * R + by + tx] = tile[tx][i];
}

// ---------------------------------------------------------------------------
// Wq transpose with K-pad: src [2400,2048] fp32 -> dst [2048,2560] bf16,
// rows (k) >= 2400 zero-filled.  Grid (2048/32, 2560/32).
// ---------------------------------------------------------------------------
__global__ __launch_bounds__(256)
void transpose_cvt_padK(const float* __restrict__ src, u16* __restrict__ dst) {
    __shared__ u16 tile[32][33];
    const int bx = blockIdx.x * 32, by = blockIdx.y * 32;   // bx: n, by: k
    const int tx = threadIdx.x & 31, ty = threadIdx.x >> 5;
    #pragma unroll
    for (int i = ty; i < 32; i += 8) {
        const int k = by + i;
        tile[i][tx] = (k < 2400) ? f2b(src[(size_t)k * 2048 + bx + tx]) : (u16)0;
    }
    __syncthreads();
    #pragma unroll
    for (int i = ty; i < 32; i += 8) dst[(size_t)(bx + i) * 2560 + by + tx] = tile[tx][i];
}

// ---------------------------------------------------------------------------
// TN MFMA GEMM: C[M,N] = A[M,K] * Bt[N,K]^T   (bf16 in, fp32 acc)
// 128x128 tile, BK=64, 4 waves 2x2, per iter 2x(4x4) 16x16x32 MFMA.
// Stage = 4 sub-tiles [A0|A1|B0|B1] of 128x32 u16 (sub-tiling keeps the
// bank-balanced 64-B row stride AND global_load_lds lane-contiguity).
// 2 stages (64 KB LDS). One barrier per BK=64 iter; vmcnt(0) drains the
// DMA issued one full compute-window earlier (latency covered by MFMA).
// EPI: 1 = splitK fp32 partial, 2 = +bias then *qmul -> bf16, 0 = bf16.
// ---------------------------------------------------------------------------
template<int EPI>
__global__ __launch_bounds__(256)
void gemm_tn(const u16* __restrict__ A, const u16* __restrict__ Bt,
             int M, int N, int K, int kLen,
             float* __restrict__ Cf, u16* __restrict__ Cb,
             const float* __restrict__ bias, const float* __restrict__ qmul)
{
    __shared__ __align__(16) u16 lds[2 * 16384];   // 64 KB

    const int t    = threadIdx.x;
    const int lane = t & 63;
    const int wave = t >> 6;
    const int wr = wave >> 1, wc = wave & 1;
    const int quad = lane >> 4, l16 = lane & 15;
    const int rowBase = blockIdx.y * 128;
    const int colBase = blockIdx.x * 128;
    const int k0 = blockIdx.z * kLen;

    // staging: wave w owns rows [w*32, w*32+32); per sub-tile 2 DMA of 16 rows.
    const u16* gA0 = A  + (size_t)(rowBase + wave * 32 + (lane >> 2)) * K + k0 + (lane & 3) * 8;
    const u16* gA1 = gA0 + 16 * (size_t)K;
    const u16* gB0 = Bt + (size_t)(colBase + wave * 32 + (lane >> 2)) * K + k0 + (lane & 3) * 8;
    const u16* gB1 = gB0 + 16 * (size_t)K;
    const int ro = wave * 1024;   // 32 rows * 32 u16

    int afr[4], bfr[4];
    #pragma unroll
    for (int r = 0; r < 4; r++) afr[r] = (wr * 64 + r * 16 + l16) * 32 + quad * 8;
    #pragma unroll
    for (int c = 0; c < 4; c++) bfr[c] = 8192 + (wc * 64 + c * 16 + l16) * 32 + quad * 8;

    f32x4 acc[4][4];
    #pragma unroll
    for (int r = 0; r < 4; r++)
        #pragma unroll
        for (int c = 0; c < 4; c++)
            acc[r][c] = (f32x4){0.f, 0.f, 0.f, 0.f};

    auto gld = [](const u16* g, u16* s) {
        __builtin_amdgcn_global_load_lds(
            (const __attribute__((address_space(1))) void*)g,
            (__attribute__((address_space(3))) void*)s, 16, 0, 0);
    };
    auto dma_stage = [&](int it, int st) {
        const int kk = it * 64;
        const int bo = st * 16384;
        gld(gA0 + kk,      &lds[bo + ro]);
        gld(gA1 + kk,      &lds[bo + ro + 512]);
        gld(gA0 + kk + 32, &lds[bo + 4096 + ro]);
        gld(gA1 + kk + 32, &lds[bo + 4096 + ro + 512]);
        gld(gB0 + kk,      &lds[bo + 8192 + ro]);
        gld(gB1 + kk,      &lds[bo + 8192 + ro + 512]);
        gld(gB0 + kk + 32, &lds[bo + 12288 + ro]);
        gld(gB1 + kk + 32, &lds[bo + 12288 + ro + 512]);
    };

    const int nIter = kLen >> 6;   // kLen % 64 == 0 for all call sites
    dma_stage(0, 0);

    for (int it = 0; it < nIter; ++it) {
        asm volatile("s_waitcnt vmcnt(0)\n\ts_barrier" ::: "memory");
        if (it + 1 < nIter) dma_stage(it + 1, (it + 1) & 1);
        const int bo = (it & 1) * 16384;
        #pragma unroll
        for (int j = 0; j < 2; j++) {
            const int so = bo + j * 4096;
            bf16x8 avf[4], bvf[4];
            #pragma unroll
            for (int r = 0; r < 4; r++) avf[r] = *(const bf16x8*)&lds[so + afr[r]];
            #pragma unroll
            for (int c = 0; c < 4; c++) bvf[c] = *(const bf16x8*)&lds[so + bfr[c]];
            #pragma unroll
            for (int r = 0; r < 4; r++)
                #pragma unroll
                for (int c = 0; c < 4; c++)
                    acc[r][c] = __builtin_amdgcn_mfma_f32_16x16x32_bf16(avf[r], bvf[c], acc[r][c], 0, 0, 0);
        }
    }

    // epilogue: D row = quad*4+reg, col = l16
    #pragma unroll
    for (int r = 0; r < 4; r++) {
        const int mBase = rowBase + wr * 64 + r * 16 + quad * 4;
        #pragma unroll
        for (int c = 0; c < 4; c++) {
            const int n = colBase + wc * 64 + c * 16 + l16;
            #pragma unroll
            for (int e = 0; e < 4; e++) {
                const int m = mBase + e;
                float v = acc[r][c][e];
                if (EPI == 1) {
                    Cf[((size_t)blockIdx.z * M + m) * N + n] = v;
                } else if (EPI == 2) {
                    v += bias[n];
                    v *= qmul[(size_t)(m / NOBJ) * N + n];
                    Cb[(size_t)m * N + n] = f2b(v);
                } else {
                    Cb[(size_t)m * N + n] = f2b(v);
                }
            }
        }
    }
}

// ---------------------------------------------------------------------------
__global__ __launch_bounds__(256)
void qcombine(const float* __restrict__ p, const float* __restrict__ bias,
              float* __restrict__ q, int MN, int S)
{
    const int i = blockIdx.x * 256 + threadIdx.x;
    float s = 0.f;
    for (int z = 0; z < S; z++) s += p[(size_t)z * MN + i];
    q[i] = s + bias[i & 2047];
}

// ---------------------------------------------------------------------------
// al_s / al_d (layer-3 only): per (node, head) dot of h[n,hd,:] with a vecs.
// ---------------------------------------------------------------------------
template<int H, int C>
__global__ __launch_bounds__(H * 64)
void al_kernel(const u16* __restrict__ h, const float* __restrict__ a_s,
               const float* __restrict__ a_d, float* __restrict__ als, float* __restrict__ ald)
{
    const int n = blockIdx.x;
    const int wv = threadIdx.x >> 6, lane = threadIdx.x & 63;
    constexpr int PL = C / 64;
    const u16*   hp  = h   + (size_t)n * (H * C) + wv * C + lane * PL;
    const float* asp = a_s + wv * C + lane * PL;
    const float* adp = a_d + wv * C + lane * PL;
    u16 hb[PL];
    if constexpr (PL == 4) { *(uint2*)hb = *(const uint2*)hp; }
    else                   { *(uint4*)hb = *(const uint4*)hp; }
    float s1 = 0.f, s2 = 0.f;
    #pragma unroll
    for (int i = 0; i < PL; i++) {
        const float hv = b2f(hb[i]);
        s1 += hv * asp[i];
        s2 += hv * adp[i];
    }
    #pragma unroll
    for (int off = 32; off > 0; off >>= 1) {
        s1 += __shfl_down(s1, off);
        s2 += __shfl_down(s2, off);
    }
    if (lane == 0) { als[n * H + wv] = s1; ald[n * H + wv] = s2; }
}

// ---------------------------------------------------------------------------
// Attention + aggregate per (image, head), WITH FUSED al computation.
// MODE 1: relu(agg+b) -> g (bf16);  MODE 2: relu(agg+b)+resid -> g
// ---------------------------------------------------------------------------
template<int H, int C, int MODE>
__global__ __launch_bounds__(256)
void attn_kernel(const u16* __restrict__ h, const float* __restrict__ a_src,
                 const float* __restrict__ a_dst, const float* __restrict__ bias,
                 const u16* __restrict__ resid, u16* __restrict__ outb)
{
    __shared__ __align__(16) u16 hl[36 * C];
    __shared__ float alpha[36 * 36];
    __shared__ float asl[36], adl[36];
    __shared__ float psum[36][8][2];
    const int b = blockIdx.y, hd = blockIdx.x;
    const int t = threadIdx.x;
    const int nb = b * NOBJ;
    constexpr int CH = C / 8;
    for (int e = t; e < 36 * CH; e += 256) {
        const int row = e / CH, col = (e - row * CH) * 8;
        *(uint4*)&hl[row * C + col] = *(const uint4*)&h[(size_t)(nb + row) * (H * C) + hd * C + col];
    }
    __syncthreads();
    constexpr int SEG = C / 8;
    for (int e = t; e < 36 * 8; e += 256) {
        const int n = e >> 3, sg = e & 7;
        const u16*   hp = &hl[n * C + sg * SEG];
        const float* as = a_src + hd * C + sg * SEG;
        const float* ad = a_dst + hd * C + sg * SEG;
        float s1 = 0.f, s2 = 0.f;
        #pragma unroll 8
        for (int i = 0; i < SEG; i++) {
            const float hv = b2f(hp[i]);
            s1 += hv * as[i]; s2 += hv * ad[i];
        }
        psum[n][sg][0] = s1; psum[n][sg][1] = s2;
    }
    __syncthreads();
    if (t < 36) {
        float s1 = 0.f, s2 = 0.f;
        #pragma unroll
        for (int sg = 0; sg < 8; sg++) { s1 += psum[t][sg][0]; s2 += psum[t][sg][1]; }
        asl[t] = s1; adl[t] = s2;
    }
    __syncthreads();
    if (t < 36) {
        const float ad = adl[t];
        float mx = -1e30f;
        for (int s = 0; s < 36; s++) {
            float v = asl[s] + ad; v = (v > 0.f) ? v : 0.2f * v;
            alpha[t * 36 + s] = v; mx = fmaxf(mx, v);
        }
        float sum = 0.f;
        for (int s = 0; s < 36; s++) { const float ex = expf(alpha[t * 36 + s] - mx); alpha[t * 36 + s] = ex; sum += ex; }
        const float inv = 1.f / (sum + 1e-16f);
        for (int s = 0; s < 36; s++) alpha[t * 36 + s] *= inv;
    }
    __syncthreads();
    constexpr int NC4 = C / 4;
    for (int e = t; e < 36 * NC4; e += 256) {
        const int d = e / NC4, c4 = (e - d * NC4) * 4;
        float a0 = 0, a1 = 0, a2 = 0, a3 = 0;
        for (int s = 0; s < 36; s++) {
            const float al = alpha[d * 36 + s];
            const ushort4 hv = *(const ushort4*)&hl[s * C + c4];
            a0 += al * b2f(hv.x); a1 += al * b2f(hv.y); a2 += al * b2f(hv.z); a3 += al * b2f(hv.w);
        }
        const int n = nb + d;
        const size_t base = (size_t)n * (H * C) + hd * C + c4;
        const int bb = hd * C + c4;
        float v0 = a0 + bias[bb + 0];
        float v1 = a1 + bias[bb + 1];
        float v2 = a2 + bias[bb + 2];
        float v3 = a3 + bias[bb + 3];
        v0 = v0 > 0.f ? v0 : 0.f; v1 = v1 > 0.f ? v1 : 0.f;
        v2 = v2 > 0.f ? v2 : 0.f; v3 = v3 > 0.f ? v3 : 0.f;
        if (MODE == 2) {
            v0 += b2f(resid[base + 0]); v1 += b2f(resid[base + 1]);
            v2 += b2f(resid[base + 2]); v3 += b2f(resid[base + 3]);
        }
        outb[base + 0] = f2b(v0); outb[base + 1] = f2b(v1);
        outb[base + 2] = f2b(v2); outb[base + 3] = f2b(v3);
    }
}

// ---------------------------------------------------------------------------
// Layer-3 attention: 5 heads, C=512, mean over heads + b3 -> fp32 d_out.
// ---------------------------------------------------------------------------
__global__ __launch_bounds__(256)
void attn_mean_kernel(const u16* __restrict__ h, const float* __restrict__ als,
                      const float* __restrict__ ald, const float* __restrict__ b3,
                      float* __restrict__ outp)
{
    __shared__ __align__(16) u16 hl[36 * 256];
    __shared__ float alpha[36 * 36];
    __shared__ float asl[36], adl[36];
    __shared__ float oacc[36 * 256];
    const int b = blockIdx.y, ch = blockIdx.x;
    const int t = threadIdx.x;
    const int nb = b * NOBJ, cbase = ch * 256;
    for (int e = t; e < 36 * 256; e += 256) oacc[e] = 0.f;
    for (int hd = 0; hd < 5; hd++) {
        __syncthreads();
        if (t < 36) { asl[t] = als[(nb + t) * 5 + hd]; adl[t] = ald[(nb + t) * 5 + hd]; }
        for (int e = t; e < 36 * 32; e += 256) {
            const int row = e >> 5, col = (e & 31) * 8;
            *(uint4*)&hl[row * 256 + col] = *(const uint4*)&h[(size_t)(nb + row) * 2560 + hd * 512 + cbase + col];
        }
        __syncthreads();
        if (t < 36) {
            const float ad = adl[t];
            float mx = -1e30f;
            for (int s = 0; s < 36; s++) {
                float v = asl[s] + ad; v = (v > 0.f) ? v : 0.2f * v;
                alpha[t * 36 + s] = v; mx = fmaxf(mx, v);
            }
            float sum = 0.f;
            for (int s = 0; s < 36; s++) { const float ex = expf(alpha[t * 36 + s] - mx); alpha[t * 36 + s] = ex; sum += ex; }
            const float inv = 1.f / (sum + 1e-16f);
            for (int s = 0; s < 36; s++) alpha[t * 36 + s] *= inv;
        }
        __syncthreads();
        for (int e = t; e < 36 * 64; e += 256) {
            const int d = e >> 6, c4 = (e & 63) * 4;
            float a0 = 0, a1 = 0, a2 = 0, a3 = 0;
            for (int s = 0; s < 36; s++) {
                const float al = alpha[d * 36 + s];
                const ushort4 hv = *(const ushort4*)&hl[s * 256 + c4];
                a0 += al * b2f(hv.x); a1 += al * b2f(hv.y); a2 += al * b2f(hv.z); a3 += al * b2f(hv.w);
            }
            oacc[d * 256 + c4 + 0] += a0; oacc[d * 256 + c4 + 1] += a1;
            oacc[d * 256 + c4 + 2] += a2; oacc[d * 256 + c4 + 3] += a3;
        }
    }
    __syncthreads();
    for (int e = t; e < 36 * 64; e += 256) {
        const int d = e >> 6, c4 = (e & 63) * 4;
        #pragma unroll
        for (int j = 0; j < 4; j++)
            outp[(size_t)(nb + d) * 512 + cbase + c4 + j] =
                oacc[d * 256 + c4 + j] * 0.2f + b3[cbase + c4 + j];
    }
}

// ---------------------------------------------------------------------------
// All inputs fp32, output fp32.  Workspace ~62.2 MB, lifetime-packed:
//  E: qe_c(padded 2560) 0.66M | of_c 18.87M
//  A: WqT(2048x2560) -> (qpart @ +10.5M) -> x -> g1 -> h3   (23.59M)
//  B: WvT | q(@ +8.39M) -> W1T -> W2T -> g2                 ( 9.44M)
//  C: h1 -> h2 -> W3T                                       ( 9.44M)
//  D: als, ald
// ---------------------------------------------------------------------------
extern "C" void kernel_launch(void* const* d_in, const int* in_sizes, int n_in,
                              void* d_out, int out_size, void* d_ws, size_t ws_size,
                              hipStream_t stream)
{
    const float* qe  = (const float*)d_in[0];    // [128,2400]
    const float* of  = (const float*)d_in[1];    // [4608,2048]
    const float* Wq  = (const float*)d_in[3];    // [2400,2048]
    const float* bq  = (const float*)d_in[4];
    const float* Wv  = (const float*)d_in[5];    // [2048,2048]
    const float* bv  = (const float*)d_in[6];
    const float* W1  = (const float*)d_in[7];    // [2048,1024]
    const float* a1s = (const float*)d_in[8];
    const float* a1d = (const float*)d_in[9];
    const float* b1  = (const float*)d_in[10];
    const float* W2  = (const float*)d_in[11];   // [1024,1024]
    const float* a2s = (const float*)d_in[12];
    const float* a2d = (const float*)d_in[13];
    const float* b2  = (const float*)d_in[14];
    const float* W3  = (const float*)d_in[15];   // [1024,2560]
    const float* a3s = (const float*)d_in[16];
    const float* a3d = (const float*)d_in[17];
    const float* b3  = (const float*)d_in[18];
    float* out = (float*)d_out;
    (void)ws_size; (void)in_sizes; (void)n_in; (void)out_size;

    char* W0 = (char*)d_ws;
    size_t off = 0;
    auto alloc = [&](size_t bytes) -> char* {
        char* p = W0 + off; off += (bytes + 255) & ~(size_t)255; return p;
    };
    u16* qe_c = (u16*)alloc(128ull * 2560 * 2);
    u16* of_c = (u16*)alloc(4608ull * 2048 * 2);
    const size_t szA = 4608ull * 2560 * 2;
    const size_t szB = 4608ull * 1024 * 2;
    const size_t szC = 4608ull * 1024 * 2;
    char* Abase = alloc(szA);
    char* Bbase = alloc(szB);
    char* Cbase = alloc(szC);
    char* Dbase = alloc((size_t)NNODE * 5 * 4 * 2);

    u16*   WqT   = (u16*)Abase;                           // [2048,2560] S1-S2
    float* qpart = (float*)(Abase + 2048ull * 2560 * 2);  // S2-S3 (5.2MB fits: 10.5+5.2<23.6)
    u16*   x     = (u16*)Abase;                           // S5-S7
    u16*   g1    = (u16*)Abase;                           // S9-S13
    u16*   h3    = (u16*)Abase;                           // S15-S17
    u16*   WvT   = (u16*)Bbase;                           // S4-S5
    float* q     = (float*)(Bbase + 2048ull * 2048 * 2);  // S3-S5
    u16*   W1T   = (u16*)Bbase;                           // S6-S7
    u16*   W2T   = (u16*)Bbase;                           // S10-S11
    u16*   g2    = (u16*)Bbase;                           // S13-S15
    u16*   h1    = (u16*)Cbase;                           // S7-S9
    u16*   h2    = (u16*)Cbase;                           // S11-S13
    u16*   W3T   = (u16*)Cbase;                           // S14-S15
    float* als   = (float*)Dbase;
    float* ald   = (float*)(Dbase + (size_t)NNODE * 5 * 4);

    // S0: canonicalize activations to bf16 (qe K-padded to 2560)
    conv_pad_qe<<<(128 * 2560 + 255) / 256, 256, 0, stream>>>(qe, qe_c);
    conv_mat<<<(4608 * 2048 / 4 + 255) / 256, 256, 0, stream>>>(of, of_c, 4608 * 2048 / 4);

    // S1-S3: q = qe @ Wq + bq   (K padded 2400->2560, splitK=5 x 512)
    transpose_cvt_padK<<<dim3(64, 80), 256, 0, stream>>>(Wq, WqT);
    gemm_tn<1><<<dim3(16, 1, 5), 256, 0, stream>>>(qe_c, WqT, 128, 2048, 2560, 512,
                                                   qpart, nullptr, nullptr, nullptr);
    qcombine<<<dim3(128 * 2048 / 256), 256, 0, stream>>>(qpart, bq, q, 128 * 2048, 5);

    // S4-S5: x = (of @ Wv + bv) * q_rep
    transpose_cvt<<<dim3(64, 64), 256, 0, stream>>>(Wv, WvT, 2048, 2048);
    gemm_tn<2><<<dim3(16, 36, 1), 256, 0, stream>>>(of_c, WvT, 4608, 2048, 2048, 2048,
                                                    nullptr, x, bv, q);

    // S6-S9: layer 1 (al fused into attn)
    transpose_cvt<<<dim3(32, 64), 256, 0, stream>>>(W1, W1T, 2048, 1024);
    gemm_tn<0><<<dim3(8, 36, 1), 256, 0, stream>>>(x, W1T, 4608, 1024, 2048, 2048,
                                                   nullptr, h1, nullptr, nullptr);
    attn_kernel<4, 256, 1><<<dim3(4, B_IMG), 256, 0, stream>>>(h1, a1s, a1d, b1, nullptr, g1);

    // S10-S13: layer 2 (+ residual g1, al fused)
    transpose_cvt<<<dim3(32, 32), 256, 0, stream>>>(W2, W2T, 1024, 1024);
    gemm_tn<0><<<dim3(8, 36, 1), 256, 0, stream>>>(g1, W2T, 4608, 1024, 1024, 1024,
                                                   nullptr, h2, nullptr, nullptr);
    attn_kernel<4, 256, 2><<<dim3(4, B_IMG), 256, 0, stream>>>(h2, a2s, a2d, b2, g1, g2);

    // S14-S17: layer 3 (5 heads, mean + b3) -> fp32 out
    transpose_cvt<<<dim3(80, 32), 256, 0, stream>>>(W3, W3T, 1024, 2560);
    gemm_tn<0><<<dim3(20, 36, 1), 256, 0, stream>>>(g2, W3T, 4608, 2560, 1024, 1024,
                                                    nullptr, h3, nullptr, nullptr);
    al_kernel<5, 512><<<dim3(NNODE), 320, 0, stream>>>(h3, a3s, a3d, als, ald);
    attn_mean_kernel<<<dim3(2, B_IMG), 256, 0, stream>>>(h3, als, ald, b3, out);
}